// Round 1
// baseline (363.121 us; speedup 1.0000x reference)
//
#include <hip/hip_runtime.h>

#define HH 1024
#define WW 1024
#define NPIX (HH * WW)

// One thread per pixel. Weights staged in LDS (wave-uniform broadcast reads).
// w1 folded: perception = [sx, sx, idc] -> w1eff[j][c<16] = w1[j,c] + w1[j,c+16],
//            w1eff[j][16+c] = w1[j,32+c].
// w2 transposed in LDS: s_w2t[j*16 + c] = w2[c*128 + j] so per-j reads are contiguous.
__global__ __launch_bounds__(256) void ca_step_kernel(
    const float* __restrict__ input,   // [16][H][W]
    const float* __restrict__ stoch,   // [H][W]
    const float* __restrict__ w1,      // [128][48]
    const float* __restrict__ b1,      // [128]
    const float* __restrict__ w2,      // [16][128]
    const float* __restrict__ b2,      // [16]
    float* __restrict__ out)           // [16][H][W]
{
    __shared__ float s_w1[128 * 32];
    __shared__ float s_w2t[128 * 16];
    __shared__ float s_b1[128];
    __shared__ float s_b2[16];

    const int t = threadIdx.x;

    // Stage weights into LDS
    for (int i = t; i < 128 * 32; i += 256) {
        int j = i >> 5;
        int c = i & 31;
        float v;
        if (c < 16) v = w1[j * 48 + c] + w1[j * 48 + 16 + c];
        else        v = w1[j * 48 + 32 + (c - 16)];
        s_w1[i] = v;
    }
    for (int i = t; i < 128 * 16; i += 256) {
        int j = i >> 4;
        int c = i & 15;
        s_w2t[i] = w2[c * 128 + j];
    }
    if (t < 128) s_b1[t] = b1[t];
    if (t < 16)  s_b2[t] = b2[t];
    __syncthreads();

    const int pix = blockIdx.x * 256 + t;
    const int y = pix >> 10;
    const int x = pix & (WW - 1);

    const bool xl = (x > 0), xr = (x < WW - 1);
    const bool yu = (y > 0), yd = (y < HH - 1);

    float sx[16], idc[16];

    #pragma unroll
    for (int c = 0; c < 16; ++c) {
        const float* p = input + c * NPIX + pix;
        float center = p[0];
        // Cross-correlation with fx = [[1,0,-1],[2,0,-2],[1,0,-1]], zero padding
        float a  = (xl && yu) ? p[-WW - 1] : 0.f;
        float bb = (xr && yu) ? p[-WW + 1] : 0.f;
        float cl = xl ? p[-1] : 0.f;
        float cr = xr ? p[+1] : 0.f;
        float dl = (xl && yd) ? p[WW - 1] : 0.f;
        float dr = (xr && yd) ? p[WW + 1] : 0.f;
        float s = (a - bb) + 2.f * (cl - cr) + (dl - dr);
        sx[c]  = fminf(fmaxf(s, 0.f), 1.f);
        idc[c] = fminf(fmaxf(center, 0.f), 1.f);
    }

    // alive: 3x3 maxpool of channel 3 (valid-only at borders), > 0.1
    float alive;
    {
        const float* p = input + 3 * NPIX + pix;
        float m = p[0];
        if (xl) m = fmaxf(m, p[-1]);
        if (xr) m = fmaxf(m, p[+1]);
        if (yu) {
            m = fmaxf(m, p[-WW]);
            if (xl) m = fmaxf(m, p[-WW - 1]);
            if (xr) m = fmaxf(m, p[-WW + 1]);
        }
        if (yd) {
            m = fmaxf(m, p[WW]);
            if (xl) m = fmaxf(m, p[WW - 1]);
            if (xr) m = fmaxf(m, p[WW + 1]);
        }
        alive = (m > 0.1f) ? 1.f : 0.f;
    }

    // MLP: h = relu(w1eff @ [sx;idc] + b1); acc = w2 @ h + b2
    float acc[16];
    #pragma unroll
    for (int c = 0; c < 16; ++c) acc[c] = s_b2[c];

    #pragma unroll 2
    for (int j = 0; j < 128; ++j) {
        float h = s_b1[j];
        const float4* wr = reinterpret_cast<const float4*>(s_w1 + j * 32);
        #pragma unroll
        for (int q = 0; q < 4; ++q) {
            float4 wv = wr[q];
            h += sx[q * 4 + 0] * wv.x + sx[q * 4 + 1] * wv.y +
                 sx[q * 4 + 2] * wv.z + sx[q * 4 + 3] * wv.w;
        }
        #pragma unroll
        for (int q = 0; q < 4; ++q) {
            float4 wv = wr[4 + q];
            h += idc[q * 4 + 0] * wv.x + idc[q * 4 + 1] * wv.y +
                 idc[q * 4 + 2] * wv.z + idc[q * 4 + 3] * wv.w;
        }
        h = fmaxf(h, 0.f);
        const float4* w2r = reinterpret_cast<const float4*>(s_w2t + j * 16);
        #pragma unroll
        for (int q = 0; q < 4; ++q) {
            float4 wv = w2r[q];
            acc[q * 4 + 0] += h * wv.x;
            acc[q * 4 + 1] += h * wv.y;
            acc[q * 4 + 2] += h * wv.z;
            acc[q * 4 + 3] += h * wv.w;
        }
    }

    const float mask = (stoch[pix] < 0.5f) ? 1.f : 0.f;

    #pragma unroll
    for (int c = 0; c < 16; ++c) {
        float v = (acc[c] * mask + idc[c]) * alive;
        v = fminf(fmaxf(v, 0.f), 1.f);
        out[c * NPIX + pix] = v;
    }
}

extern "C" void kernel_launch(void* const* d_in, const int* in_sizes, int n_in,
                              void* d_out, int out_size, void* d_ws, size_t ws_size,
                              hipStream_t stream) {
    const float* input = (const float*)d_in[0];
    const float* stoch = (const float*)d_in[1];
    const float* w1    = (const float*)d_in[2];
    const float* b1    = (const float*)d_in[3];
    const float* w2    = (const float*)d_in[4];
    const float* b2    = (const float*)d_in[5];
    float* out = (float*)d_out;

    dim3 grid(NPIX / 256);
    dim3 block(256);
    hipLaunchKernelGGL(ca_step_kernel, grid, block, 0, stream,
                       input, stoch, w1, b1, w2, b2, out);
}

// Round 4
// 198.616 us; speedup vs baseline: 1.8283x; 1.8283x over previous
//
#include <hip/hip_runtime.h>

#define HH 1024
#define WW 1024
#define NPIX (HH * WW)

typedef __bf16 bf8 __attribute__((ext_vector_type(8)));
typedef float  f4  __attribute__((ext_vector_type(4)));

static __device__ __forceinline__ float bf2f(unsigned short s) {
    unsigned u = ((unsigned)s) << 16;
    return __builtin_bit_cast(float, u);
}
static __device__ __forceinline__ unsigned short f2bf(float f) {
    unsigned u = __builtin_bit_cast(unsigned, f);
    u += 0x7fffu + ((u >> 16) & 1u);   // round to nearest even
    return (unsigned short)(u >> 16);
}
static __device__ __forceinline__ unsigned packbf2(float a, float b) {
    return (unsigned)f2bf(a) | ((unsigned)f2bf(b) << 16);
}

// Block = 256 threads = 4 waves = 256 pixels (one 256-wide x-segment, fixed y).
// Phase 1: per-thread Sobel/clip/alive/mask; pack P=[sx(16),idc(16)] bf16 into LDS.
// Phase 2: per-wave MFMA: H^T = W1eff @ P^T (8x mfma 16x16x32, bias in C),
//          relu->bf16->LDS(H, xor-swizzled)->B-frags, out = W2 @ H^T (4x mfma).
__global__ __launch_bounds__(256) void ca_mfma_kernel(
    const float* __restrict__ input,   // [16][H][W]
    const float* __restrict__ stoch,   // [H][W]
    const float* __restrict__ w1,      // [128][48]
    const float* __restrict__ b1,      // [128]
    const float* __restrict__ w2,      // [16][128]
    const float* __restrict__ b2,      // [16]
    float* __restrict__ out)           // [16][H][W]
{
    __shared__ __align__(16) unsigned short s_P[256 * 40];   // rows 80 B (pad: 2-way banks)
    __shared__ __align__(16) unsigned short s_W1[128 * 40];  // W1eff bf16, rows 80 B
    __shared__ __align__(16) unsigned short s_W2[16 * 128];  // W2 bf16, rows 256 B
    __shared__ __align__(16) unsigned short s_H[4 * 2048];   // 4 KB per wave, xor-swizzled
    __shared__ float s_mask[256];
    __shared__ float s_alive[256];

    const int t = threadIdx.x;

    // ---- stage folded W1eff (128x32) as bf16 ----
    for (int i = t; i < 128 * 16; i += 256) {
        int j = i >> 4, k = (i & 15) * 2;
        const float* row = w1 + j * 48;
        float v0, v1;
        if (k < 16) { v0 = row[k] + row[k + 16];  v1 = row[k + 1] + row[k + 17]; }
        else        { v0 = row[k + 16];           v1 = row[k + 17]; }          // k in [16,32) -> w1 col k+16
        *reinterpret_cast<unsigned*>(&s_W1[j * 40 + k]) = packbf2(v0, v1);
    }
    // ---- stage W2 (16x128) as bf16 ----
    for (int i = t; i < 16 * 64; i += 256) {
        int c = i >> 6, j = (i & 63) * 2;
        *reinterpret_cast<unsigned*>(&s_W2[c * 128 + j]) = packbf2(w2[c * 128 + j], w2[c * 128 + j + 1]);
    }

    // ---- phase 1: Sobel / clip / alive / mask for this thread's pixel ----
    const int pix = blockIdx.x * 256 + t;
    const int y = pix >> 10;
    const int x = pix & (WW - 1);
    const bool xl = (x > 0), xr = (x < WW - 1);
    const bool yu = (y > 0), yd = (y < HH - 1);

    float sx[16], idc[16];
    #pragma unroll
    for (int c = 0; c < 16; ++c) {
        const float* ip = input + c * NPIX + pix;
        float center = ip[0];
        float a  = (xl && yu) ? ip[-WW - 1] : 0.f;
        float bb = (xr && yu) ? ip[-WW + 1] : 0.f;
        float cl = xl ? ip[-1] : 0.f;
        float cr = xr ? ip[+1] : 0.f;
        float dl = (xl && yd) ? ip[WW - 1] : 0.f;
        float dr = (xr && yd) ? ip[WW + 1] : 0.f;
        float s = (a - bb) + 2.f * (cl - cr) + (dl - dr);
        sx[c]  = fminf(fmaxf(s, 0.f), 1.f);
        idc[c] = fminf(fmaxf(center, 0.f), 1.f);
    }
    {
        const float* ip = input + 3 * NPIX + pix;
        float m = ip[0];
        if (xl) m = fmaxf(m, ip[-1]);
        if (xr) m = fmaxf(m, ip[+1]);
        if (yu) {
            m = fmaxf(m, ip[-WW]);
            if (xl) m = fmaxf(m, ip[-WW - 1]);
            if (xr) m = fmaxf(m, ip[-WW + 1]);
        }
        if (yd) {
            m = fmaxf(m, ip[WW]);
            if (xl) m = fmaxf(m, ip[WW - 1]);
            if (xr) m = fmaxf(m, ip[WW + 1]);
        }
        s_alive[t] = (m > 0.1f) ? 1.f : 0.f;
    }
    s_mask[t] = (stoch[pix] < 0.5f) ? 1.f : 0.f;

    // pack P row (k<16: sx, k>=16: idc), 64 B as 4x b128
    {
        unsigned prow[16];
        #pragma unroll
        for (int q = 0; q < 8; ++q) prow[q]     = packbf2(sx[2 * q],  sx[2 * q + 1]);
        #pragma unroll
        for (int q = 0; q < 8; ++q) prow[8 + q] = packbf2(idc[2 * q], idc[2 * q + 1]);
        #pragma unroll
        for (int qq = 0; qq < 4; ++qq)
            *reinterpret_cast<uint4*>(&s_P[t * 40 + qq * 8]) =
                make_uint4(prow[4*qq], prow[4*qq+1], prow[4*qq+2], prow[4*qq+3]);
    }

    __syncthreads();   // weights + P + mask/alive visible

    // ---- phase 2: MFMA ----
    const int w  = t >> 6;
    const int l  = t & 63;
    const int p  = l & 15;   // col (pixel-in-tile) / A-row
    const int g  = l >> 4;   // lane group -> k-chunk
    const int swz = (p & 7) << 4;

    // A-frags: W1eff rows 16*t8+p, k-chunk g  (lane: row=l%16, k=8*(l/16)+e)
    bf8 af1[8];
    #pragma unroll
    for (int t8 = 0; t8 < 8; ++t8)
        af1[t8] = *reinterpret_cast<const bf8*>(&s_W1[(16 * t8 + p) * 40 + g * 8]);
    // A-frags: W2 row c=p, k j = 32*kt + 8g..+8
    bf8 af2[4];
    #pragma unroll
    for (int kt = 0; kt < 4; ++kt)
        af2[kt] = *reinterpret_cast<const bf8*>(&s_W2[p * 128 + kt * 32 + g * 8]);
    // bias C-inputs: b1f[t8][r] = b1[16*t8+4g+r]; b2f[r] = b2[4g+r]
    f4 b1f[8];
    #pragma unroll
    for (int t8 = 0; t8 < 8; ++t8)
        b1f[t8] = *reinterpret_cast<const f4*>(b1 + 16 * t8 + 4 * g);
    f4 b2f = *reinterpret_cast<const f4*>(b2 + 4 * g);

    unsigned short* sHw = &s_H[w * 2048];

    for (int u = 0; u < 4; ++u) {
        const int rowP = w * 64 + u * 16 + p;
        // B-frag: P^T[k=8g+e][pix=rowP]
        bf8 bP = *reinterpret_cast<const bf8*>(&s_P[rowP * 40 + g * 8]);

        f4 acc1[8];
        #pragma unroll
        for (int t8 = 0; t8 < 8; ++t8)
            acc1[t8] = __builtin_amdgcn_mfma_f32_16x16x32_bf16(af1[t8], bP, b1f[t8], 0, 0, 0);

        // lane holds H^T[j=16*t8+4g+r][pix p]; relu -> bf16 -> swizzled LDS
        #pragma unroll
        for (int t8 = 0; t8 < 8; ++t8) {
            float h0 = fmaxf(acc1[t8][0], 0.f), h1 = fmaxf(acc1[t8][1], 0.f);
            float h2 = fmaxf(acc1[t8][2], 0.f), h3 = fmaxf(acc1[t8][3], 0.f);
            unsigned u0 = packbf2(h0, h1), u1 = packbf2(h2, h3);
            int off = (p * 256 + 32 * t8 + 8 * g) ^ swz;
            *reinterpret_cast<uint2*>(reinterpret_cast<char*>(sHw) + off) = make_uint2(u0, u1);
        }
        __syncthreads();

        f4 acc2 = b2f;
        #pragma unroll
        for (int kt = 0; kt < 4; ++kt) {
            int off = (p * 256 + 64 * kt + 16 * g) ^ swz;
            bf8 bH = *reinterpret_cast<const bf8*>(reinterpret_cast<char*>(sHw) + off);
            acc2 = __builtin_amdgcn_mfma_f32_16x16x32_bf16(af2[kt], bH, acc2, 0, 0, 0);
        }

        // epilogue: lane has channels c=4g+r for pixel rowP
        float mk = s_mask[rowP];
        float al = s_alive[rowP];
        uint2 idcu = *reinterpret_cast<const uint2*>(
            reinterpret_cast<const char*>(s_P) + rowP * 80 + 32 + 8 * g);
        float id0 = bf2f((unsigned short)(idcu.x & 0xffff));
        float id1 = bf2f((unsigned short)(idcu.x >> 16));
        float id2 = bf2f((unsigned short)(idcu.y & 0xffff));
        float id3 = bf2f((unsigned short)(idcu.y >> 16));

        const int pixg = blockIdx.x * 256 + rowP;
        float v0 = fminf(fmaxf((acc2[0] * mk + id0) * al, 0.f), 1.f);
        float v1 = fminf(fmaxf((acc2[1] * mk + id1) * al, 0.f), 1.f);
        float v2 = fminf(fmaxf((acc2[2] * mk + id2) * al, 0.f), 1.f);
        float v3 = fminf(fmaxf((acc2[3] * mk + id3) * al, 0.f), 1.f);
        out[(4 * g + 0) * NPIX + pixg] = v0;
        out[(4 * g + 1) * NPIX + pixg] = v1;
        out[(4 * g + 2) * NPIX + pixg] = v2;
        out[(4 * g + 3) * NPIX + pixg] = v3;

        __syncthreads();   // protect s_H WAR before next tile's writes
    }
}

extern "C" void kernel_launch(void* const* d_in, const int* in_sizes, int n_in,
                              void* d_out, int out_size, void* d_ws, size_t ws_size,
                              hipStream_t stream) {
    const float* input = (const float*)d_in[0];
    const float* stoch = (const float*)d_in[1];
    const float* w1    = (const float*)d_in[2];
    const float* b1    = (const float*)d_in[3];
    const float* w2    = (const float*)d_in[4];
    const float* b2    = (const float*)d_in[5];
    float* out = (float*)d_out;

    dim3 grid(NPIX / 256);
    dim3 block(256);
    hipLaunchKernelGGL(ca_mfma_kernel, grid, block, 0, stream,
                       input, stoch, w1, b1, w2, b2, out);
}

// Round 5
// 196.317 us; speedup vs baseline: 1.8497x; 1.0117x over previous
//
#include <hip/hip_runtime.h>

#define HH 1024
#define WW 1024
#define NPIX (HH * WW)

typedef __bf16 bf8 __attribute__((ext_vector_type(8)));
typedef float  f4  __attribute__((ext_vector_type(4)));

static __device__ __forceinline__ float bf2f(unsigned short s) {
    unsigned u = ((unsigned)s) << 16;
    return __builtin_bit_cast(float, u);
}
static __device__ __forceinline__ unsigned short f2bf(float f) {
    unsigned u = __builtin_bit_cast(unsigned, f);
    u += 0x7fffu + ((u >> 16) & 1u);   // round to nearest even
    return (unsigned short)(u >> 16);
}
static __device__ __forceinline__ unsigned packbf2(float a, float b) {
    return (unsigned)f2bf(a) | ((unsigned)f2bf(b) << 16);
}

// Block = 256 threads = 4 waves = 256 pixels (one 256-wide x-segment, fixed y).
// Phase 1: per-thread Sobel/clip/alive/mask; pack P=[sx(16),idc(16)] bf16 into LDS.
// Phase 2: per-wave MFMA. All phase-2 LDS traffic is wave-local:
//   - P rows / mask / alive / idc for rowP in [w*64, w*64+64) -> written by this wave
//   - s_H slice is per-wave private
// => only ONE __syncthreads (for the cooperatively staged weights).
// H buffer swizzle: full 4-bit XOR  off = (p*256 + L) ^ (p<<4)
//   read slot (4kt+g)^p is a bijection over 16 slots per 16-lane group -> 2-way max (free).
__global__ __launch_bounds__(256) void ca_mfma_kernel(
    const float* __restrict__ input,   // [16][H][W]
    const float* __restrict__ stoch,   // [H][W]
    const float* __restrict__ w1,      // [128][48]
    const float* __restrict__ b1,      // [128]
    const float* __restrict__ w2,      // [16][128]
    const float* __restrict__ b2,      // [16]
    float* __restrict__ out)           // [16][H][W]
{
    __shared__ __align__(16) unsigned short s_P[256 * 40];   // rows 80 B
    __shared__ __align__(16) unsigned short s_W1[128 * 40];  // W1eff bf16, rows 80 B
    __shared__ __align__(16) unsigned short s_W2[16 * 128];  // W2 bf16, rows 256 B
    __shared__ __align__(16) unsigned short s_H[4 * 2048];   // 4 KB per wave, xor-swizzled
    __shared__ float s_mask[256];
    __shared__ float s_alive[256];

    const int t = threadIdx.x;

    // ---- stage folded W1eff (128x32) as bf16 ----
    for (int i = t; i < 128 * 16; i += 256) {
        int j = i >> 4, k = (i & 15) * 2;
        const float* row = w1 + j * 48;
        float v0, v1;
        if (k < 16) { v0 = row[k] + row[k + 16];  v1 = row[k + 1] + row[k + 17]; }
        else        { v0 = row[k + 16];           v1 = row[k + 17]; }   // k in [16,32) -> w1 col k+16
        *reinterpret_cast<unsigned*>(&s_W1[j * 40 + k]) = packbf2(v0, v1);
    }
    // ---- stage W2 (16x128) as bf16 ----
    for (int i = t; i < 16 * 64; i += 256) {
        int c = i >> 6, j = (i & 63) * 2;
        *reinterpret_cast<unsigned*>(&s_W2[c * 128 + j]) = packbf2(w2[c * 128 + j], w2[c * 128 + j + 1]);
    }

    // ---- phase 1: Sobel / clip / alive / mask for this thread's pixel ----
    const int pix = blockIdx.x * 256 + t;
    const int y = pix >> 10;
    const int x = pix & (WW - 1);
    const bool xl = (x > 0), xr = (x < WW - 1);
    const bool yu = (y > 0), yd = (y < HH - 1);

    float sx[16], idc[16];
    #pragma unroll
    for (int c = 0; c < 16; ++c) {
        const float* ip = input + c * NPIX + pix;
        float center = ip[0];
        float a  = (xl && yu) ? ip[-WW - 1] : 0.f;
        float bb = (xr && yu) ? ip[-WW + 1] : 0.f;
        float cl = xl ? ip[-1] : 0.f;
        float cr = xr ? ip[+1] : 0.f;
        float dl = (xl && yd) ? ip[WW - 1] : 0.f;
        float dr = (xr && yd) ? ip[WW + 1] : 0.f;
        float s = (a - bb) + 2.f * (cl - cr) + (dl - dr);
        sx[c]  = fminf(fmaxf(s, 0.f), 1.f);
        idc[c] = fminf(fmaxf(center, 0.f), 1.f);
    }
    {
        const float* ip = input + 3 * NPIX + pix;
        float m = ip[0];
        if (xl) m = fmaxf(m, ip[-1]);
        if (xr) m = fmaxf(m, ip[+1]);
        if (yu) {
            m = fmaxf(m, ip[-WW]);
            if (xl) m = fmaxf(m, ip[-WW - 1]);
            if (xr) m = fmaxf(m, ip[-WW + 1]);
        }
        if (yd) {
            m = fmaxf(m, ip[WW]);
            if (xl) m = fmaxf(m, ip[WW - 1]);
            if (xr) m = fmaxf(m, ip[WW + 1]);
        }
        s_alive[t] = (m > 0.1f) ? 1.f : 0.f;
    }
    s_mask[t] = (stoch[pix] < 0.5f) ? 1.f : 0.f;

    // pack P row (k<16: sx, k>=16: idc), 64 B as 4x b128
    {
        unsigned prow[16];
        #pragma unroll
        for (int q = 0; q < 8; ++q) prow[q]     = packbf2(sx[2 * q],  sx[2 * q + 1]);
        #pragma unroll
        for (int q = 0; q < 8; ++q) prow[8 + q] = packbf2(idc[2 * q], idc[2 * q + 1]);
        #pragma unroll
        for (int qq = 0; qq < 4; ++qq)
            *reinterpret_cast<uint4*>(&s_P[t * 40 + qq * 8]) =
                make_uint4(prow[4*qq], prow[4*qq+1], prow[4*qq+2], prow[4*qq+3]);
    }

    __syncthreads();   // the ONLY barrier: weights (+ P/mask/alive, conservatively) visible

    // ---- phase 2: MFMA ----
    const int w  = t >> 6;
    const int l  = t & 63;
    const int p  = l & 15;   // col (pixel-in-tile) / A-row
    const int g  = l >> 4;   // lane group -> k-chunk
    const int swz = p << 4;  // full 4-bit slot swizzle (16 slots of 16B per 256B row)

    // A-frags: W1eff rows 16*t8+p, k-chunk g  (lane: row=l%16, k=8*(l/16)+e)
    bf8 af1[8];
    #pragma unroll
    for (int t8 = 0; t8 < 8; ++t8)
        af1[t8] = *reinterpret_cast<const bf8*>(&s_W1[(16 * t8 + p) * 40 + g * 8]);
    // A-frags: W2 row c=p, k j = 32*kt + 8g..+8
    bf8 af2[4];
    #pragma unroll
    for (int kt = 0; kt < 4; ++kt)
        af2[kt] = *reinterpret_cast<const bf8*>(&s_W2[p * 128 + kt * 32 + g * 8]);
    // bias C-inputs: b1f[t8][r] = b1[16*t8+4g+r]; b2f[r] = b2[4g+r]
    f4 b1f[8];
    #pragma unroll
    for (int t8 = 0; t8 < 8; ++t8)
        b1f[t8] = *reinterpret_cast<const f4*>(b1 + 16 * t8 + 4 * g);
    f4 b2f = *reinterpret_cast<const f4*>(b2 + 4 * g);

    unsigned short* sHw = &s_H[w * 2048];

    for (int u = 0; u < 4; ++u) {
        const int rowP = w * 64 + u * 16 + p;     // always this wave's own pixels
        // B-frag: P^T[k=8g+e][pix=rowP]
        bf8 bP = *reinterpret_cast<const bf8*>(&s_P[rowP * 40 + g * 8]);

        f4 acc1[8];
        #pragma unroll
        for (int t8 = 0; t8 < 8; ++t8)
            acc1[t8] = __builtin_amdgcn_mfma_f32_16x16x32_bf16(af1[t8], bP, b1f[t8], 0, 0, 0);

        // lane holds H^T[j=16*t8+4g+r][pix p]; relu -> bf16 -> swizzled wave-private LDS
        __builtin_amdgcn_sched_barrier(0);   // keep writes below prior iter's reads
        #pragma unroll
        for (int t8 = 0; t8 < 8; ++t8) {
            float h0 = fmaxf(acc1[t8][0], 0.f), h1 = fmaxf(acc1[t8][1], 0.f);
            float h2 = fmaxf(acc1[t8][2], 0.f), h3 = fmaxf(acc1[t8][3], 0.f);
            unsigned u0 = packbf2(h0, h1), u1 = packbf2(h2, h3);
            int off = (p * 256 + 32 * t8 + 8 * g) ^ swz;
            *reinterpret_cast<uint2*>(reinterpret_cast<char*>(sHw) + off) = make_uint2(u0, u1);
        }
        // cross-LANE (same-wave) dependency: wait for this wave's LDS writes,
        // and fence the compiler (it cannot see the cross-lane dep — rule #18).
        asm volatile("s_waitcnt lgkmcnt(0)" ::: "memory");
        __builtin_amdgcn_sched_barrier(0);

        f4 acc2 = b2f;
        #pragma unroll
        for (int kt = 0; kt < 4; ++kt) {
            int off = (p * 256 + 64 * kt + 16 * g) ^ swz;
            bf8 bH = *reinterpret_cast<const bf8*>(reinterpret_cast<char*>(sHw) + off);
            acc2 = __builtin_amdgcn_mfma_f32_16x16x32_bf16(af2[kt], bH, acc2, 0, 0, 0);
        }

        // epilogue: lane has channels c=4g+r for pixel rowP (wave-local data)
        float mk = s_mask[rowP];
        float al = s_alive[rowP];
        uint2 idcu = *reinterpret_cast<const uint2*>(
            reinterpret_cast<const char*>(s_P) + rowP * 80 + 32 + 8 * g);
        float id0 = bf2f((unsigned short)(idcu.x & 0xffff));
        float id1 = bf2f((unsigned short)(idcu.x >> 16));
        float id2 = bf2f((unsigned short)(idcu.y & 0xffff));
        float id3 = bf2f((unsigned short)(idcu.y >> 16));

        const int pixg = blockIdx.x * 256 + rowP;
        float v0 = fminf(fmaxf((acc2[0] * mk + id0) * al, 0.f), 1.f);
        float v1 = fminf(fmaxf((acc2[1] * mk + id1) * al, 0.f), 1.f);
        float v2 = fminf(fmaxf((acc2[2] * mk + id2) * al, 0.f), 1.f);
        float v3 = fminf(fmaxf((acc2[3] * mk + id3) * al, 0.f), 1.f);
        out[(4 * g + 0) * NPIX + pixg] = v0;
        out[(4 * g + 1) * NPIX + pixg] = v1;
        out[(4 * g + 2) * NPIX + pixg] = v2;
        out[(4 * g + 3) * NPIX + pixg] = v3;
    }
}

extern "C" void kernel_launch(void* const* d_in, const int* in_sizes, int n_in,
                              void* d_out, int out_size, void* d_ws, size_t ws_size,
                              hipStream_t stream) {
    const float* input = (const float*)d_in[0];
    const float* stoch = (const float*)d_in[1];
    const float* w1    = (const float*)d_in[2];
    const float* b1    = (const float*)d_in[3];
    const float* w2    = (const float*)d_in[4];
    const float* b2    = (const float*)d_in[5];
    float* out = (float*)d_out;

    dim3 grid(NPIX / 256);
    dim3 block(256);
    hipLaunchKernelGGL(ca_mfma_kernel, grid, block, 0, stream,
                       input, stoch, w1, b1, w2, b2, out);
}

// Round 9
// 181.942 us; speedup vs baseline: 1.9958x; 1.0790x over previous
//
#include <hip/hip_runtime.h>

#define HH 1024
#define WW 1024
#define NPIX (HH * WW)

typedef __bf16 bf8 __attribute__((ext_vector_type(8)));
typedef float  f4  __attribute__((ext_vector_type(4)));
typedef unsigned uv4 __attribute__((ext_vector_type(4)));

static __device__ __forceinline__ float bf2f(unsigned short s) {
    unsigned u = ((unsigned)s) << 16;
    return __builtin_bit_cast(float, u);
}
static __device__ __forceinline__ unsigned short f2bf(float f) {
    unsigned u = __builtin_bit_cast(unsigned, f);
    u += 0x7fffu + ((u >> 16) & 1u);   // round to nearest even
    return (unsigned short)(u >> 16);
}
static __device__ __forceinline__ unsigned packbf2(float a, float b) {
    return (unsigned)f2bf(a) | ((unsigned)f2bf(b) << 16);
}

// Block = 256 threads = 4 waves = 256 pixels.
// Layer-1 MFMAs compute W1eff rows in permuted order sigma(t8,m) =
//   32*(t8&3) + 8*(m>>2) + 4*(t8>>2) + (m&3)
// so that lane (p,g)'s acc1[kt]/acc1[kt+4] registers ARE layer-2's B-fragment
// for k-tile kt (j = 32*kt + 8*g + e). No H LDS buffer, no write->read drain.
// sigma is applied at W1 staging (slot = sigma^-1(j)) and to b1 offsets.
__global__ __launch_bounds__(256, 4) void ca_mfma_kernel(
    const float* __restrict__ input,   // [16][H][W]
    const float* __restrict__ stoch,   // [H][W]
    const float* __restrict__ w1,      // [128][48]
    const float* __restrict__ b1,      // [128]
    const float* __restrict__ w2,      // [16][128]
    const float* __restrict__ b2,      // [16]
    float* __restrict__ out)           // [16][H][W]
{
    __shared__ __align__(16) unsigned short s_P[256 * 40];   // 20480 B, rows 80 B
    __shared__ __align__(16) unsigned short s_W1[128 * 40];  // 10240 B, sigma-permuted
    __shared__ __align__(16) unsigned short s_W2[16 * 128];  // 4096 B
    __shared__ float s_mask[256];                            // 1024 B
    __shared__ float s_alive[256];                           // 1024 B
    // total 36864 B -> 4 blocks/CU

    const int t = threadIdx.x;

    // ---- stage folded W1eff (128x32) as bf16, permuted: row j -> slot (t8*16+m) ----
    for (int i = t; i < 128 * 16; i += 256) {
        int j = i >> 4, k = (i & 15) * 2;
        const float* row = w1 + j * 48;
        float v0, v1;
        if (k < 16) { v0 = row[k] + row[k + 16];  v1 = row[k + 1] + row[k + 17]; }
        else        { v0 = row[k + 16];           v1 = row[k + 17]; }   // k in [16,32) -> w1 col k+16
        int t8 = ((j >> 5) & 3) | (((j >> 2) & 1) << 2);
        int m  = (((j >> 3) & 3) << 2) | (j & 3);
        *reinterpret_cast<unsigned*>(&s_W1[(t8 * 16 + m) * 40 + k]) = packbf2(v0, v1);
    }
    // ---- stage W2 (16x128) as bf16 ----
    for (int i = t; i < 16 * 64; i += 256) {
        int c = i >> 6, j = (i & 63) * 2;
        *reinterpret_cast<unsigned*>(&s_W2[c * 128 + j]) = packbf2(w2[c * 128 + j], w2[c * 128 + j + 1]);
    }

    // ---- phase 1: Sobel / clip / alive / mask for this thread's pixel ----
    const int pix = blockIdx.x * 256 + t;
    const int y = pix >> 10;
    const int x = pix & (WW - 1);
    const bool xl = (x > 0), xr = (x < WW - 1);
    const bool yu = (y > 0), yd = (y < HH - 1);

    float sx[16], idc[16];
    #pragma unroll
    for (int c = 0; c < 16; ++c) {
        const float* ip = input + c * NPIX + pix;
        float center = ip[0];
        float a  = (xl && yu) ? ip[-WW - 1] : 0.f;
        float bb = (xr && yu) ? ip[-WW + 1] : 0.f;
        float cl = xl ? ip[-1] : 0.f;
        float cr = xr ? ip[+1] : 0.f;
        float dl = (xl && yd) ? ip[WW - 1] : 0.f;
        float dr = (xr && yd) ? ip[WW + 1] : 0.f;
        float s = (a - bb) + 2.f * (cl - cr) + (dl - dr);
        sx[c]  = fminf(fmaxf(s, 0.f), 1.f);
        idc[c] = fminf(fmaxf(center, 0.f), 1.f);
    }
    {
        const float* ip = input + 3 * NPIX + pix;
        float m = ip[0];
        if (xl) m = fmaxf(m, ip[-1]);
        if (xr) m = fmaxf(m, ip[+1]);
        if (yu) {
            m = fmaxf(m, ip[-WW]);
            if (xl) m = fmaxf(m, ip[-WW - 1]);
            if (xr) m = fmaxf(m, ip[-WW + 1]);
        }
        if (yd) {
            m = fmaxf(m, ip[WW]);
            if (xl) m = fmaxf(m, ip[WW - 1]);
            if (xr) m = fmaxf(m, ip[WW + 1]);
        }
        s_alive[t] = (m > 0.1f) ? 1.f : 0.f;
    }
    s_mask[t] = (stoch[pix] < 0.5f) ? 1.f : 0.f;

    // pack P row (k<16: sx, k>=16: idc), 64 B as 4x b128
    {
        unsigned prow[16];
        #pragma unroll
        for (int q = 0; q < 8; ++q) prow[q]     = packbf2(sx[2 * q],  sx[2 * q + 1]);
        #pragma unroll
        for (int q = 0; q < 8; ++q) prow[8 + q] = packbf2(idc[2 * q], idc[2 * q + 1]);
        #pragma unroll
        for (int qq = 0; qq < 4; ++qq)
            *reinterpret_cast<uint4*>(&s_P[t * 40 + qq * 8]) =
                make_uint4(prow[4*qq], prow[4*qq+1], prow[4*qq+2], prow[4*qq+3]);
    }

    __syncthreads();   // the ONLY barrier

    // ---- phase 2: MFMA ----
    const int w  = t >> 6;
    const int l  = t & 63;
    const int p  = l & 15;   // col (pixel-in-tile) / A-row
    const int g  = l >> 4;   // lane group -> k-chunk

    // A-frags: permuted W1eff slot rows (t8*16+p), chunk g
    bf8 af1[8];
    #pragma unroll
    for (int t8 = 0; t8 < 8; ++t8)
        af1[t8] = *reinterpret_cast<const bf8*>(&s_W1[(16 * t8 + p) * 40 + g * 8]);
    // A-frags: W2 row c=p, k = 32*kt + 8g..+8
    bf8 af2[4];
    #pragma unroll
    for (int kt = 0; kt < 4; ++kt)
        af2[kt] = *reinterpret_cast<const bf8*>(&s_W2[p * 128 + kt * 32 + g * 8]);
    // bias C-inputs follow sigma: b1f[t8][r] = b1[32*(t8&3) + 8g + 4*(t8>>2) + r]
    f4 b1f[8];
    #pragma unroll
    for (int t8 = 0; t8 < 8; ++t8)
        b1f[t8] = *reinterpret_cast<const f4*>(b1 + 32 * (t8 & 3) + 8 * g + 4 * (t8 >> 2));
    f4 b2f = *reinterpret_cast<const f4*>(b2 + 4 * g);

    #pragma unroll
    for (int u = 0; u < 4; ++u) {
        const int rowP = w * 64 + u * 16 + p;     // this wave's own pixels
        // B-frag: P^T[k=8g+e][pix=rowP]
        bf8 bP = *reinterpret_cast<const bf8*>(&s_P[rowP * 40 + g * 8]);

        f4 acc2 = b2f;
        #pragma unroll
        for (int kt = 0; kt < 4; ++kt) {
            // layer-1: lane(p,g) gets H[32kt+8g+{0..3}] (h0) and H[32kt+8g+4+{0..3}] (h1)
            f4 h0 = __builtin_amdgcn_mfma_f32_16x16x32_bf16(af1[kt],     bP, b1f[kt],     0, 0, 0);
            f4 h1 = __builtin_amdgcn_mfma_f32_16x16x32_bf16(af1[kt + 4], bP, b1f[kt + 4], 0, 0, 0);
            // relu + pack: this IS layer-2's B-frag for k-tile kt, in-lane
            unsigned q0 = packbf2(fmaxf(h0[0], 0.f), fmaxf(h0[1], 0.f));
            unsigned q1 = packbf2(fmaxf(h0[2], 0.f), fmaxf(h0[3], 0.f));
            unsigned q2 = packbf2(fmaxf(h1[0], 0.f), fmaxf(h1[1], 0.f));
            unsigned q3 = packbf2(fmaxf(h1[2], 0.f), fmaxf(h1[3], 0.f));
            uv4 bv = {q0, q1, q2, q3};
            bf8 bH = __builtin_bit_cast(bf8, bv);
            acc2 = __builtin_amdgcn_mfma_f32_16x16x32_bf16(af2[kt], bH, acc2, 0, 0, 0);
        }

        // epilogue: lane has channels c=4g+r for pixel rowP (wave-local data)
        float mk = s_mask[rowP];
        float al = s_alive[rowP];
        uint2 idcu = *reinterpret_cast<const uint2*>(
            reinterpret_cast<const char*>(s_P) + rowP * 80 + 32 + 8 * g);
        float id0 = bf2f((unsigned short)(idcu.x & 0xffff));
        float id1 = bf2f((unsigned short)(idcu.x >> 16));
        float id2 = bf2f((unsigned short)(idcu.y & 0xffff));
        float id3 = bf2f((unsigned short)(idcu.y >> 16));

        const int pixg = blockIdx.x * 256 + rowP;
        float v0 = fminf(fmaxf((acc2[0] * mk + id0) * al, 0.f), 1.f);
        float v1 = fminf(fmaxf((acc2[1] * mk + id1) * al, 0.f), 1.f);
        float v2 = fminf(fmaxf((acc2[2] * mk + id2) * al, 0.f), 1.f);
        float v3 = fminf(fmaxf((acc2[3] * mk + id3) * al, 0.f), 1.f);
        out[(4 * g + 0) * NPIX + pixg] = v0;
        out[(4 * g + 1) * NPIX + pixg] = v1;
        out[(4 * g + 2) * NPIX + pixg] = v2;
        out[(4 * g + 3) * NPIX + pixg] = v3;
    }
}

extern "C" void kernel_launch(void* const* d_in, const int* in_sizes, int n_in,
                              void* d_out, int out_size, void* d_ws, size_t ws_size,
                              hipStream_t stream) {
    const float* input = (const float*)d_in[0];
    const float* stoch = (const float*)d_in[1];
    const float* w1    = (const float*)d_in[2];
    const float* b1    = (const float*)d_in[3];
    const float* w2    = (const float*)d_in[4];
    const float* b2    = (const float*)d_in[5];
    float* out = (float*)d_out;

    dim3 grid(NPIX / 256);
    dim3 block(256);
    hipLaunchKernelGGL(ca_mfma_kernel, grid, block, 0, stream,
                       input, stoch, w1, b1, w2, b2, out);
}